// Round 5
// baseline (50.567 us; speedup 1.0000x reference)
//
#include <hip/hip_runtime.h>

#define NUM_FREQ 32
#define KU 16  // float4 elements per thread

typedef float vfloat4 __attribute__((ext_vector_type(4)));

// Phase-separated streaming kernel.
// Each block of 256 threads handles 4096 consecutive float4 (= 128 sp-rows),
// sharing one (b,c) (128 | 512 with 128-aligned start => single c; single b).
// Per wave: build M in registers -> 16-load read burst -> in-place matvecs
// -> sched_barrier -> 16-store write burst. Long same-direction bursts per
// wave minimize read/write turnaround on the HBM path.
__global__ void __launch_bounds__(256)
camfreq_fused_kernel(const vfloat4* __restrict__ feats,
                     const float* __restrict__ matrix,
                     const float* __restrict__ L_params,
                     const float* __restrict__ D_params,
                     const float* __restrict__ U_params,
                     vfloat4* __restrict__ out) {
    const int t    = threadIdx.x;
    const int base = blockIdx.x * (256 * KU);   // float4 index, max 8,388,608 -> fits int

    // Wave-uniform (b,c).
    const int sp0 = base >> 5;        // (b*16+n)*4096 + s
    const int s0  = sp0 & 4095;
    const int b   = sp0 >> 16;
    const int c   = s0 >> 9;

    // ---- Phase 0: per-lane build of M = (L_f diag(e^D_f) U_f) @ matrix[b,c].
    const int f = t & (NUM_FREQ - 1);
    const float l0 = L_params[f * 6 + 0], l1 = L_params[f * 6 + 1];
    const float l2 = L_params[f * 6 + 2], l3 = L_params[f * 6 + 3];
    const float l4 = L_params[f * 6 + 4], l5 = L_params[f * 6 + 5];
    const float e0 = __expf(D_params[f * 4 + 0]);
    const float e1 = __expf(D_params[f * 4 + 1]);
    const float e2 = __expf(D_params[f * 4 + 2]);
    const float e3 = __expf(D_params[f * 4 + 3]);
    const float u0 = U_params[f * 6 + 0], u1 = U_params[f * 6 + 1];
    const float u2 = U_params[f * 6 + 2], u3 = U_params[f * 6 + 3];
    const float u4 = U_params[f * 6 + 4], u5 = U_params[f * 6 + 5];

    float fr[4][4];
    fr[0][0] = e0;      fr[0][1] = e0 * u0;  fr[0][2] = e0 * u1;            fr[0][3] = e0 * u2;
    fr[1][0] = l0 * e0;
    fr[1][1] = l0 * e0 * u0 + e1;
    fr[1][2] = l0 * e0 * u1 + e1 * u3;
    fr[1][3] = l0 * e0 * u2 + e1 * u4;
    fr[2][0] = l1 * e0;
    fr[2][1] = l1 * e0 * u0 + l2 * e1;
    fr[2][2] = l1 * e0 * u1 + l2 * e1 * u3 + e2;
    fr[2][3] = l1 * e0 * u2 + l2 * e1 * u4 + e2 * u5;
    fr[3][0] = l3 * e0;
    fr[3][1] = l3 * e0 * u0 + l4 * e1;
    fr[3][2] = l3 * e0 * u1 + l4 * e1 * u3 + l5 * e2;
    fr[3][3] = l3 * e0 * u2 + l4 * e1 * u4 + l5 * e2 * u5 + e3;

    const float* mt = matrix + ((b << 3) + c) * 16;   // wave-uniform -> s_load
    float M[4][4];
#pragma unroll
    for (int i = 0; i < 4; ++i) {
#pragma unroll
        for (int k = 0; k < 4; ++k) {
            M[i][k] = fr[i][0] * mt[0 * 4 + k]
                    + fr[i][1] * mt[1 * 4 + k]
                    + fr[i][2] * mt[2 * 4 + k]
                    + fr[i][3] * mt[3 * 4 + k];
        }
    }

    // ---- Phase 1: pure read burst (16 x dwordx4 nt loads back-to-back).
    vfloat4 v[KU];
#pragma unroll
    for (int k = 0; k < KU; ++k) {
        v[k] = __builtin_nontemporal_load(&feats[base + k * 256 + t]);
    }

    // ---- Phase 2: in-place matvecs (consume loads as they land).
#pragma unroll
    for (int k = 0; k < KU; ++k) {
        const vfloat4 x = v[k];
        vfloat4 o;
        o.x = M[0][0] * x.x + M[0][1] * x.y + M[0][2] * x.z + M[0][3] * x.w;
        o.y = M[1][0] * x.x + M[1][1] * x.y + M[1][2] * x.z + M[1][3] * x.w;
        o.z = M[2][0] * x.x + M[2][1] * x.y + M[2][2] * x.z + M[2][3] * x.w;
        o.w = M[3][0] * x.x + M[3][1] * x.y + M[3][2] * x.z + M[3][3] * x.w;
        v[k] = o;
    }

    // Pin the schedule: no store issues before all matvecs are placed.
    __builtin_amdgcn_sched_barrier(0);

    // ---- Phase 3: pure write burst (16 x dwordx4 nt stores back-to-back).
#pragma unroll
    for (int k = 0; k < KU; ++k) {
        __builtin_nontemporal_store(v[k], &out[base + k * 256 + t]);
    }
}

extern "C" void kernel_launch(void* const* d_in, const int* in_sizes, int n_in,
                              void* d_out, int out_size, void* d_ws, size_t ws_size,
                              hipStream_t stream) {
    const float* feats    = (const float*)d_in[0];
    const float* matrix   = (const float*)d_in[1];
    const float* L_params = (const float*)d_in[2];
    const float* D_params = (const float*)d_in[3];
    const float* U_params = (const float*)d_in[4];
    float* out = (float*)d_out;

    const int total4 = (4 * 16 * 4096 * 128) / 4;   // 8,388,608 float4
    const int block  = 256;
    const int grid   = total4 / (block * KU);       // 2048 blocks
    camfreq_fused_kernel<<<grid, block, 0, stream>>>(
        reinterpret_cast<const vfloat4*>(feats), matrix, L_params, D_params,
        U_params, reinterpret_cast<vfloat4*>(out));
}

// Round 6
// 44.535 us; speedup vs baseline: 1.1354x; 1.1354x over previous
//
#include <hip/hip_runtime.h>

#define NUM_FREQ 32
#define KU 4  // float4 elements per thread

typedef float vfloat4 __attribute__((ext_vector_type(4)));

// Streaming kernel, max-TLP variant: 8192 blocks, register-only M build,
// no LDS, no barrier. nt on loads (read-once, don't pollute L2); stores go
// through L2 (write aggregation — the harness fill kernels hit 7.1 TB/s
// through that path vs 5.7 for our nt-store variants).
__global__ void __launch_bounds__(256)
camfreq_fused_kernel(const vfloat4* __restrict__ feats,
                     const float* __restrict__ matrix,
                     const float* __restrict__ L_params,
                     const float* __restrict__ D_params,
                     const float* __restrict__ U_params,
                     vfloat4* __restrict__ out) {
    const int t    = threadIdx.x;
    const int base = blockIdx.x * (256 * KU);

    // Block-uniform (b,c): 1024 float4 = 32 sp-rows, aligned, within one c.
    const int sp0 = base >> 5;        // (b*16+n)*4096 + s
    const int s0  = sp0 & 4095;
    const int b   = sp0 >> 16;
    const int c   = s0 >> 9;

    // Issue streaming loads first; M build hides under their latency.
    vfloat4 v[KU];
#pragma unroll
    for (int k = 0; k < KU; ++k) {
        v[k] = __builtin_nontemporal_load(&feats[base + k * 256 + t]);
    }

    // Per-lane register build of M = (L_f diag(e^D_f) U_f) @ matrix[b,c].
    const int f = t & (NUM_FREQ - 1);
    const float l0 = L_params[f * 6 + 0], l1 = L_params[f * 6 + 1];
    const float l2 = L_params[f * 6 + 2], l3 = L_params[f * 6 + 3];
    const float l4 = L_params[f * 6 + 4], l5 = L_params[f * 6 + 5];
    const float e0 = __expf(D_params[f * 4 + 0]);
    const float e1 = __expf(D_params[f * 4 + 1]);
    const float e2 = __expf(D_params[f * 4 + 2]);
    const float e3 = __expf(D_params[f * 4 + 3]);
    const float u0 = U_params[f * 6 + 0], u1 = U_params[f * 6 + 1];
    const float u2 = U_params[f * 6 + 2], u3 = U_params[f * 6 + 3];
    const float u4 = U_params[f * 6 + 4], u5 = U_params[f * 6 + 5];

    float fr[4][4];
    fr[0][0] = e0;      fr[0][1] = e0 * u0;  fr[0][2] = e0 * u1;            fr[0][3] = e0 * u2;
    fr[1][0] = l0 * e0;
    fr[1][1] = l0 * e0 * u0 + e1;
    fr[1][2] = l0 * e0 * u1 + e1 * u3;
    fr[1][3] = l0 * e0 * u2 + e1 * u4;
    fr[2][0] = l1 * e0;
    fr[2][1] = l1 * e0 * u0 + l2 * e1;
    fr[2][2] = l1 * e0 * u1 + l2 * e1 * u3 + e2;
    fr[2][3] = l1 * e0 * u2 + l2 * e1 * u4 + e2 * u5;
    fr[3][0] = l3 * e0;
    fr[3][1] = l3 * e0 * u0 + l4 * e1;
    fr[3][2] = l3 * e0 * u1 + l4 * e1 * u3 + l5 * e2;
    fr[3][3] = l3 * e0 * u2 + l4 * e1 * u4 + l5 * e2 * u5 + e3;

    const float* mt = matrix + ((b << 3) + c) * 16;   // wave-uniform -> s_load
    float M[4][4];
#pragma unroll
    for (int i = 0; i < 4; ++i) {
#pragma unroll
        for (int k = 0; k < 4; ++k) {
            M[i][k] = fr[i][0] * mt[0 * 4 + k]
                    + fr[i][1] * mt[1 * 4 + k]
                    + fr[i][2] * mt[2 * 4 + k]
                    + fr[i][3] * mt[3 * 4 + k];
        }
    }

    // Matvec + store per k; stores NOT nontemporal (use L2 write aggregation).
#pragma unroll
    for (int k = 0; k < KU; ++k) {
        const vfloat4 x = v[k];
        vfloat4 o;
        o.x = M[0][0] * x.x + M[0][1] * x.y + M[0][2] * x.z + M[0][3] * x.w;
        o.y = M[1][0] * x.x + M[1][1] * x.y + M[1][2] * x.z + M[1][3] * x.w;
        o.z = M[2][0] * x.x + M[2][1] * x.y + M[2][2] * x.z + M[2][3] * x.w;
        o.w = M[3][0] * x.x + M[3][1] * x.y + M[3][2] * x.z + M[3][3] * x.w;
        out[base + k * 256 + t] = o;
    }
}

extern "C" void kernel_launch(void* const* d_in, const int* in_sizes, int n_in,
                              void* d_out, int out_size, void* d_ws, size_t ws_size,
                              hipStream_t stream) {
    const float* feats    = (const float*)d_in[0];
    const float* matrix   = (const float*)d_in[1];
    const float* L_params = (const float*)d_in[2];
    const float* D_params = (const float*)d_in[3];
    const float* U_params = (const float*)d_in[4];
    float* out = (float*)d_out;

    const int total4 = (4 * 16 * 4096 * 128) / 4;   // 8,388,608 float4
    const int block  = 256;
    const int grid   = total4 / (block * KU);       // 8192 blocks
    camfreq_fused_kernel<<<grid, block, 0, stream>>>(
        reinterpret_cast<const vfloat4*>(feats), matrix, L_params, D_params,
        U_params, reinterpret_cast<vfloat4*>(out));
}